// Round 1
// baseline (286.792 us; speedup 1.0000x reference)
//
#include <hip/hip_runtime.h>

// EfficientPairEmbed: out[0, e, h] = sum_g emb[anum[src_e], anum[dst_e], 0, h, g] * rbf[e, g]
// rbf[e,g] = exp(-0.5/std^2 * (dist_e - offset_g)^2), offsets = linspace(0, 12, 50), std = 12/50.

#define G_NUM 50
#define H_NUM 8
#define NE_NUM 100
#define EDGES_PER_BLOCK 32
#define BLOCK_THREADS 256

__global__ __launch_bounds__(BLOCK_THREADS) void pair_embed_kernel(
    const int* __restrict__ anum,
    const int* __restrict__ edge_index,
    const float* __restrict__ dist,
    const float* __restrict__ emb,
    float* __restrict__ out,
    int n_edges)
{
    __shared__ int   pair_s[EDGES_PER_BLOCK];                // (src*100+dst)*400 base offset
    __shared__ float dist_s[EDGES_PER_BLOCK];
    __shared__ float rbf_s[EDGES_PER_BLOCK * G_NUM];         // [32][50] floats, 6.4 KB

    const int tid = threadIdx.x;
    const int e0  = blockIdx.x * EDGES_PER_BLOCK;

    // Phase 1: stage per-edge pair base + dist.
    if (tid < EDGES_PER_BLOCK) {
        int e = e0 + tid;
        if (e >= n_edges) e = n_edges - 1;                   // clamp (E divisible by 32 anyway)
        int s  = edge_index[e];
        int d  = edge_index[n_edges + e];
        int sa = anum[s];
        int da = anum[d];
        pair_s[tid] = (sa * NE_NUM + da) * (H_NUM * G_NUM);
        dist_s[tid] = dist[e];
    }
    __syncthreads();

    // Phase 2: RBF once per edge, cooperatively. 1600 values / 256 threads.
    const float spacing = 12.0f / (float)(G_NUM - 1);
    const float coeff   = -0.5f * ((float)G_NUM / 12.0f) * ((float)G_NUM / 12.0f); // -0.5/std^2
    #pragma unroll
    for (int idx = tid; idx < EDGES_PER_BLOCK * G_NUM; idx += BLOCK_THREADS) {
        int el = idx / G_NUM;
        int g  = idx - el * G_NUM;
        float diff = dist_s[el] - (float)g * spacing;
        rbf_s[idx] = __expf(coeff * diff * diff);
    }
    __syncthreads();

    // Phase 3: one thread per (edge, head): 50-wide dot. float2 loads (head rows are 8B-aligned).
    const int el = tid >> 3;     // 0..31
    const int h  = tid & 7;      // 0..7
    const float* __restrict__ ebase = emb + pair_s[el] + h * G_NUM;
    const float* __restrict__ rbase = rbf_s + el * G_NUM;

    float acc = 0.0f;
    #pragma unroll
    for (int g2 = 0; g2 < G_NUM / 2; ++g2) {
        float2 ev = *(const float2*)(ebase + 2 * g2);
        float2 rv = *(const float2*)(rbase + 2 * g2);
        acc += ev.x * rv.x;
        acc += ev.y * rv.y;
    }

    int e = e0 + el;
    if (e < n_edges) {
        out[e0 * H_NUM + tid] = acc;   // == out[e*8 + h], fully coalesced
    }
}

extern "C" void kernel_launch(void* const* d_in, const int* in_sizes, int n_in,
                              void* d_out, int out_size, void* d_ws, size_t ws_size,
                              hipStream_t stream) {
    const int*   anum       = (const int*)d_in[0];
    const int*   edge_index = (const int*)d_in[1];
    const float* dist       = (const float*)d_in[2];
    const float* emb        = (const float*)d_in[3];
    float*       out        = (float*)d_out;

    const int n_edges = in_sizes[2];                  // dist has E elements
    const int grid = (n_edges + EDGES_PER_BLOCK - 1) / EDGES_PER_BLOCK;

    pair_embed_kernel<<<grid, BLOCK_THREADS, 0, stream>>>(
        anum, edge_index, dist, emb, out, n_edges);
}

// Round 2
// 211.352 us; speedup vs baseline: 1.3569x; 1.3569x over previous
//
#include <hip/hip_runtime.h>

// EfficientPairEmbed: out[0, e, h] = sum_g emb[anum[src_e], anum[dst_e], 0, h, g] * rbf[e, g]
// rbf[e,g] = exp(-0.5/std^2 * (dist_e - offset_g)^2), offsets = linspace(0, 12, 50), std = 12/50.
//
// R2 strategy: bin edges by pair id p = sa*100+da (10k pairs, ~100 edges each),
// then one block per pair loads the 1600B alpha row into LDS ONCE and processes
// all its edges. Converts the 1.6GB random gather (R1: 634MB HBM fetch) into a
// 16MB streaming read.

#define G_NUM 50
#define H_NUM 8
#define NE_NUM 100
#define N_PAIRS (NE_NUM * NE_NUM)
#define PAIR_CAP 256
#define EDGES_PER_CHUNK 32
#define BLOCK_THREADS 256

#define SPACING (12.0f / (float)(G_NUM - 1))
// std = 12/50 -> coeff = -0.5 * (50/12)^2
#define RBF_COEFF (-0.5f * ((float)G_NUM / 12.0f) * ((float)G_NUM / 12.0f))

// ---------------- Pass 1: bucket edges by pair id ----------------
__global__ __launch_bounds__(BLOCK_THREADS) void bucket_kernel(
    const int* __restrict__ anum,
    const int* __restrict__ edge_index,
    const float* __restrict__ dist,
    const float* __restrict__ emb,
    int* __restrict__ count,          // [N_PAIRS], pre-zeroed
    int2* __restrict__ bucket,        // [N_PAIRS * PAIR_CAP] {edge_id, dist_bits}
    float* __restrict__ out,          // slow-path only
    int n_edges)
{
    int e = blockIdx.x * BLOCK_THREADS + threadIdx.x;
    if (e >= n_edges) return;

    int s  = edge_index[e];
    int d  = edge_index[n_edges + e];
    int sa = anum[s];
    int da = anum[d];
    int p  = sa * NE_NUM + da;
    float dv = dist[e];

    int pos = atomicAdd(&count[p], 1);
    if (pos < PAIR_CAP) {
        int2 ent;
        ent.x = e;
        ent.y = __float_as_int(dv);
        bucket[p * PAIR_CAP + pos] = ent;
    } else {
        // Overflow slow path (statistically never hit: mean 100, cap 256).
        const float* ar = emb + (size_t)p * (H_NUM * G_NUM);
        for (int h = 0; h < H_NUM; ++h) {
            float acc = 0.0f;
            for (int g = 0; g < G_NUM; ++g) {
                float diff = dv - (float)g * SPACING;
                acc += ar[h * G_NUM + g] * __expf(RBF_COEFF * diff * diff);
            }
            out[(size_t)e * H_NUM + h] = acc;
        }
    }
}

// ---------------- Pass 2: one block per pair ----------------
__global__ __launch_bounds__(BLOCK_THREADS) void pair_compute_kernel(
    const float* __restrict__ emb,
    const int* __restrict__ count,
    const int2* __restrict__ bucket,
    float* __restrict__ out)
{
    __shared__ __align__(16) float alpha_s[H_NUM * G_NUM];       // 400 floats, 1.6 KB
    __shared__ __align__(16) float rbf_s[EDGES_PER_CHUNK * G_NUM]; // 1600 floats, 6.4 KB
    __shared__ int   eid_s[EDGES_PER_CHUNK];
    __shared__ float dist_s[EDGES_PER_CHUNK];

    const int p   = blockIdx.x;
    const int tid = threadIdx.x;

    int c = count[p];
    if (c > PAIR_CAP) c = PAIR_CAP;
    if (c == 0) return;

    // Load alpha row [8][50] into LDS (coalesced 1600B).
    #pragma unroll
    for (int idx = tid; idx < H_NUM * G_NUM; idx += BLOCK_THREADS)
        alpha_s[idx] = emb[(size_t)p * (H_NUM * G_NUM) + idx];

    const int2* __restrict__ bk = bucket + (size_t)p * PAIR_CAP;

    for (int base = 0; base < c; base += EDGES_PER_CHUNK) {
        __syncthreads();   // protect staging buffers from previous iteration readers

        int n = c - base;
        if (n > EDGES_PER_CHUNK) n = EDGES_PER_CHUNK;

        if (tid < EDGES_PER_CHUNK && tid < n) {
            int2 ent = bk[base + tid];
            eid_s[tid]  = ent.x;
            dist_s[tid] = __int_as_float(ent.y);
        }
        __syncthreads();

        // RBF for this chunk: n*50 values over 256 threads.
        for (int idx = tid; idx < n * G_NUM; idx += BLOCK_THREADS) {
            int el = idx / G_NUM;
            int g  = idx - el * G_NUM;
            float diff = dist_s[el] - (float)g * SPACING;
            rbf_s[idx] = __expf(RBF_COEFF * diff * diff);
        }
        __syncthreads();

        // One thread per (edge, head). Consecutive tid = consecutive h ->
        // 8 threads write 32B contiguous per edge.
        int el = tid >> 3;
        int h  = tid & 7;
        if (el < n) {
            const float* ab = alpha_s + h * G_NUM;
            const float* rb = rbf_s + el * G_NUM;
            float acc = 0.0f;
            #pragma unroll
            for (int g2 = 0; g2 < G_NUM / 2; ++g2) {
                float2 av = *(const float2*)(ab + 2 * g2);
                float2 rv = *(const float2*)(rb + 2 * g2);
                acc += av.x * rv.x;
                acc += av.y * rv.y;
            }
            out[(size_t)eid_s[el] * H_NUM + h] = acc;
        }
    }
}

// ---------------- Fallback (R1 kernel) if ws too small ----------------
__global__ __launch_bounds__(BLOCK_THREADS) void direct_kernel(
    const int* __restrict__ anum,
    const int* __restrict__ edge_index,
    const float* __restrict__ dist,
    const float* __restrict__ emb,
    float* __restrict__ out,
    int n_edges)
{
    __shared__ int   pair_s[32];
    __shared__ float dist_s[32];
    __shared__ float rbf_s[32 * G_NUM];

    const int tid = threadIdx.x;
    const int e0  = blockIdx.x * 32;

    if (tid < 32) {
        int e = e0 + tid;
        if (e >= n_edges) e = n_edges - 1;
        int s  = edge_index[e];
        int d  = edge_index[n_edges + e];
        pair_s[tid] = (anum[s] * NE_NUM + anum[d]) * (H_NUM * G_NUM);
        dist_s[tid] = dist[e];
    }
    __syncthreads();

    for (int idx = tid; idx < 32 * G_NUM; idx += BLOCK_THREADS) {
        int el = idx / G_NUM;
        int g  = idx - el * G_NUM;
        float diff = dist_s[el] - (float)g * SPACING;
        rbf_s[idx] = __expf(RBF_COEFF * diff * diff);
    }
    __syncthreads();

    const int el = tid >> 3;
    const int h  = tid & 7;
    const float* ebase = emb + pair_s[el] + h * G_NUM;
    const float* rbase = rbf_s + el * G_NUM;

    float acc = 0.0f;
    #pragma unroll
    for (int g2 = 0; g2 < G_NUM / 2; ++g2) {
        float2 ev = *(const float2*)(ebase + 2 * g2);
        float2 rv = *(const float2*)(rbase + 2 * g2);
        acc += ev.x * rv.x + ev.y * rv.y;
    }

    if (e0 + el < n_edges)
        out[e0 * H_NUM + tid] = acc;
}

extern "C" void kernel_launch(void* const* d_in, const int* in_sizes, int n_in,
                              void* d_out, int out_size, void* d_ws, size_t ws_size,
                              hipStream_t stream) {
    const int*   anum       = (const int*)d_in[0];
    const int*   edge_index = (const int*)d_in[1];
    const float* dist       = (const float*)d_in[2];
    const float* emb        = (const float*)d_in[3];
    float*       out        = (float*)d_out;
    const int n_edges = in_sizes[2];

    // Workspace layout: [counts: N_PAIRS ints][pad][bucket: N_PAIRS*PAIR_CAP int2]
    const size_t counts_bytes = (size_t)N_PAIRS * sizeof(int);
    const size_t bucket_off   = (counts_bytes + 1023) & ~(size_t)1023;
    const size_t need = bucket_off + (size_t)N_PAIRS * PAIR_CAP * sizeof(int2);

    if (ws_size < need) {
        // Safety fallback: direct (R1) kernel.
        const int grid = (n_edges + 31) / 32;
        direct_kernel<<<grid, BLOCK_THREADS, 0, stream>>>(
            anum, edge_index, dist, emb, out, n_edges);
        return;
    }

    int*  counts = (int*)d_ws;
    int2* bucket = (int2*)((char*)d_ws + bucket_off);

    hipMemsetAsync(counts, 0, counts_bytes, stream);

    const int grid1 = (n_edges + BLOCK_THREADS - 1) / BLOCK_THREADS;
    bucket_kernel<<<grid1, BLOCK_THREADS, 0, stream>>>(
        anum, edge_index, dist, emb, counts, bucket, out, n_edges);

    pair_compute_kernel<<<N_PAIRS, BLOCK_THREADS, 0, stream>>>(
        emb, counts, bucket, out);
}

// Round 3
// 164.585 us; speedup vs baseline: 1.7425x; 1.2842x over previous
//
#include <hip/hip_runtime.h>

// EfficientPairEmbed: out[0, e, h] = sum_g emb[anum[src_e], anum[dst_e], 0, h, g] * rbf[e, g]
// rbf[e,g] = exp(-0.5/std^2 * (dist_e - offset_g)^2), offsets = linspace(0, 12, 50), std = 12/50.
//
// R3: (1) 4 hashed sub-counters per pair to cut device-atomic same-address
// contention 4x (R2 bucket pass: VALUBusy 0.6%, atomic-return-bound).
// (2) truncated 16-wide gaussian window (std=0.245*spacing units; terms beyond
// +-7 offsets are < 2e-11) -> exp count 50M->16M, dot width 50->16.

#define G_NUM 50
#define H_NUM 8
#define NE_NUM 100
#define N_PAIRS (NE_NUM * NE_NUM)
#define SUBS 4
#define SUBCAP 60
#define WIN 16
#define RBF_STRIDE 18            // pad 16 -> 18 floats: 8 edge-rows hit distinct bank pairs
#define EDGES_PER_CHUNK 32
#define BLOCK_THREADS 256

#define SPACING (12.0f / (float)(G_NUM - 1))
#define INV_SPACING ((float)(G_NUM - 1) / 12.0f)
// std = 12/50 -> coeff = -0.5 * (50/12)^2
#define RBF_COEFF (-0.5f * ((float)G_NUM / 12.0f) * ((float)G_NUM / 12.0f))

// ---------------- Pass 1: bucket edges by (pair, sub) ----------------
__global__ __launch_bounds__(BLOCK_THREADS) void bucket_kernel(
    const int* __restrict__ anum,
    const int* __restrict__ edge_index,
    const float* __restrict__ dist,
    const float* __restrict__ emb,
    int* __restrict__ count,          // [N_PAIRS*SUBS], pre-zeroed
    int2* __restrict__ bucket,        // [N_PAIRS*SUBS*SUBCAP] {edge_id, dist_bits}
    float* __restrict__ out,          // slow-path only
    int n_edges)
{
    int e = blockIdx.x * BLOCK_THREADS + threadIdx.x;
    if (e >= n_edges) return;

    int s  = edge_index[e];
    int d  = edge_index[n_edges + e];
    int p  = anum[s] * NE_NUM + anum[d];
    float dv = dist[e];

    int sub = threadIdx.x & (SUBS - 1);
    int slot = p * SUBS + sub;
    int pos = atomicAdd(&count[slot], 1);
    if (pos < SUBCAP) {
        int2 ent;
        ent.x = e;
        ent.y = __float_as_int(dv);
        bucket[(size_t)slot * SUBCAP + pos] = ent;
    } else {
        // Overflow slow path (P ~ 1e-9 per sub-bucket; correctness safety net).
        const float* ar = emb + (size_t)p * (H_NUM * G_NUM);
        for (int h = 0; h < H_NUM; ++h) {
            float acc = 0.0f;
            for (int g = 0; g < G_NUM; ++g) {
                float diff = dv - (float)g * SPACING;
                acc += ar[h * G_NUM + g] * __expf(RBF_COEFF * diff * diff);
            }
            out[(size_t)e * H_NUM + h] = acc;
        }
    }
}

// ---------------- Pass 2: one block per pair ----------------
__global__ __launch_bounds__(BLOCK_THREADS) void pair_compute_kernel(
    const float* __restrict__ emb,
    const int* __restrict__ count,
    const int2* __restrict__ bucket,
    float* __restrict__ out)
{
    __shared__ __align__(16) float alpha_s[H_NUM * G_NUM];          // 1.6 KB
    __shared__ __align__(16) float rbf_s[EDGES_PER_CHUNK * RBF_STRIDE]; // 2.3 KB
    __shared__ int2  ent_s[SUBS * SUBCAP];                          // 1.92 KB
    __shared__ int   cbase_s[SUBS + 1];
    __shared__ int   eid_s[EDGES_PER_CHUNK];
    __shared__ float dist_s[EDGES_PER_CHUNK];
    __shared__ int   g0_s[EDGES_PER_CHUNK];

    const int p   = blockIdx.x;
    const int tid = threadIdx.x;

    if (tid == 0) {
        int acc = 0;
        #pragma unroll
        for (int s = 0; s < SUBS; ++s) {
            cbase_s[s] = acc;
            int cs = count[p * SUBS + s];
            if (cs > SUBCAP) cs = SUBCAP;
            acc += cs;
        }
        cbase_s[SUBS] = acc;
    }

    // Load alpha row [8][50] into LDS (coalesced 1600B) while tid0 scans counts.
    if (tid < (H_NUM * G_NUM) / 2)
        ((float2*)alpha_s)[tid] = ((const float2*)(emb + (size_t)p * (H_NUM * G_NUM)))[tid];

    __syncthreads();
    const int ctot = cbase_s[SUBS];
    if (ctot == 0) return;

    // Gather this pair's entries from the 4 sub-buckets into LDS.
    #pragma unroll
    for (int s = 0; s < SUBS; ++s) {
        int b0 = cbase_s[s];
        int cs = cbase_s[s + 1] - b0;
        const int2* bk = bucket + (size_t)(p * SUBS + s) * SUBCAP;
        for (int i = tid; i < cs; i += BLOCK_THREADS)
            ent_s[b0 + i] = bk[i];
    }

    for (int base = 0; base < ctot; base += EDGES_PER_CHUNK) {
        __syncthreads();

        int n = ctot - base;
        if (n > EDGES_PER_CHUNK) n = EDGES_PER_CHUNK;

        if (tid < n) {
            int2 ent = ent_s[base + tid];
            float dv = __int_as_float(ent.y);
            eid_s[tid]  = ent.x;
            dist_s[tid] = dv;
            int g0 = (int)(dv * INV_SPACING) - 7;
            if (g0 < 0) g0 = 0;
            if (g0 > G_NUM - WIN) g0 = G_NUM - WIN;
            g0_s[tid] = g0 & ~1;      // even for float2-aligned alpha reads
        }
        __syncthreads();

        // Windowed RBF: n*16 values over 256 threads.
        for (int idx = tid; idx < n * WIN; idx += BLOCK_THREADS) {
            int el = idx >> 4;
            int gw = idx & (WIN - 1);
            float diff = dist_s[el] - (float)(g0_s[el] + gw) * SPACING;
            rbf_s[el * RBF_STRIDE + gw] = __expf(RBF_COEFF * diff * diff);
        }
        __syncthreads();

        // One thread per (edge, head): 16-wide dot.
        int el = tid >> 3;
        int h  = tid & 7;
        if (el < n) {
            const float* ab = alpha_s + h * G_NUM + g0_s[el];
            const float* rb = rbf_s + el * RBF_STRIDE;
            float acc = 0.0f;
            #pragma unroll
            for (int j = 0; j < WIN / 2; ++j) {
                float2 av = *(const float2*)(ab + 2 * j);
                float2 rv = *(const float2*)(rb + 2 * j);
                acc += av.x * rv.x + av.y * rv.y;
            }
            out[(size_t)eid_s[el] * H_NUM + h] = acc;
        }
    }
}

// ---------------- Fallback (R1 kernel) if ws too small ----------------
__global__ __launch_bounds__(BLOCK_THREADS) void direct_kernel(
    const int* __restrict__ anum,
    const int* __restrict__ edge_index,
    const float* __restrict__ dist,
    const float* __restrict__ emb,
    float* __restrict__ out,
    int n_edges)
{
    __shared__ int   pair_s[32];
    __shared__ float dist_sd[32];
    __shared__ float rbf_sd[32 * G_NUM];

    const int tid = threadIdx.x;
    const int e0  = blockIdx.x * 32;

    if (tid < 32) {
        int e = e0 + tid;
        if (e >= n_edges) e = n_edges - 1;
        int s  = edge_index[e];
        int d  = edge_index[n_edges + e];
        pair_s[tid] = (anum[s] * NE_NUM + anum[d]) * (H_NUM * G_NUM);
        dist_sd[tid] = dist[e];
    }
    __syncthreads();

    for (int idx = tid; idx < 32 * G_NUM; idx += BLOCK_THREADS) {
        int el = idx / G_NUM;
        int g  = idx - el * G_NUM;
        float diff = dist_sd[el] - (float)g * SPACING;
        rbf_sd[idx] = __expf(RBF_COEFF * diff * diff);
    }
    __syncthreads();

    const int el = tid >> 3;
    const int h  = tid & 7;
    const float* ebase = emb + pair_s[el] + h * G_NUM;
    const float* rbase = rbf_sd + el * G_NUM;

    float acc = 0.0f;
    #pragma unroll
    for (int g2 = 0; g2 < G_NUM / 2; ++g2) {
        float2 ev = *(const float2*)(ebase + 2 * g2);
        float2 rv = *(const float2*)(rbase + 2 * g2);
        acc += ev.x * rv.x + ev.y * rv.y;
    }

    if (e0 + el < n_edges)
        out[e0 * H_NUM + tid] = acc;
}

extern "C" void kernel_launch(void* const* d_in, const int* in_sizes, int n_in,
                              void* d_out, int out_size, void* d_ws, size_t ws_size,
                              hipStream_t stream) {
    const int*   anum       = (const int*)d_in[0];
    const int*   edge_index = (const int*)d_in[1];
    const float* dist       = (const float*)d_in[2];
    const float* emb        = (const float*)d_in[3];
    float*       out        = (float*)d_out;
    const int n_edges = in_sizes[2];

    // Workspace: [counts: N_PAIRS*SUBS ints][pad][bucket: N_PAIRS*SUBS*SUBCAP int2]
    const size_t counts_bytes = (size_t)N_PAIRS * SUBS * sizeof(int);
    const size_t bucket_off   = (counts_bytes + 1023) & ~(size_t)1023;
    const size_t need = bucket_off + (size_t)N_PAIRS * SUBS * SUBCAP * sizeof(int2);

    if (ws_size < need) {
        const int grid = (n_edges + 31) / 32;
        direct_kernel<<<grid, BLOCK_THREADS, 0, stream>>>(
            anum, edge_index, dist, emb, out, n_edges);
        return;
    }

    int*  counts = (int*)d_ws;
    int2* bucket = (int2*)((char*)d_ws + bucket_off);

    hipMemsetAsync(counts, 0, counts_bytes, stream);

    const int grid1 = (n_edges + BLOCK_THREADS - 1) / BLOCK_THREADS;
    bucket_kernel<<<grid1, BLOCK_THREADS, 0, stream>>>(
        anum, edge_index, dist, emb, counts, bucket, out, n_edges);

    pair_compute_kernel<<<N_PAIRS, BLOCK_THREADS, 0, stream>>>(
        emb, counts, bucket, out);
}

// Round 4
// 159.321 us; speedup vs baseline: 1.8001x; 1.0330x over previous
//
#include <hip/hip_runtime.h>

// EfficientPairEmbed: out[0, e, h] = sum_g emb[anum[src_e], anum[dst_e], 0, h, g] * rbf[e, g]
// rbf[e,g] = exp(-0.5/std^2 * (dist_e - offset_g)^2), offsets = linspace(0, 12, 50), std = 12/50.
//
// R4: (1) pass A bins edges by sa (100 bins) with per-block LDS histograms ->
// 25.6k global atomics instead of 1M (R3 pass-1 was atomic-issue-bound at
// ~18 cyc/atomic/channel). (2) emb transposed to [pair][g][h] so a 16-g x 8-h
// window is 512B contiguous (8 lines) instead of ~64 scattered lines (R1
// showed the gather is TCP line-lookup bound at ~1 line/cyc/CU). (3) pass C
// in sa-major order so the 160KB sa-slice stays L2-resident.

#define G_NUM 50
#define H_NUM 8
#define NE_NUM 100
#define N_PAIRS (NE_NUM * NE_NUM)
#define WIN 16

#define ASUBS 32          // sub-buckets per sa bin (one per blockIdx&31)
#define SUBCAP 448        // entries per (sa,sub); mean ~312, +4.6 sigma
#define ABLOCKS 256       // pass-A blocks (8 per sub)
#define SA_CACHE 4096     // per-block sa cache (uchar), >= epb

#define CCHUNK 32         // edges per pass-C block
#define NCHUNK (SUBCAP / CCHUNK)   // 14

#define BLOCK_THREADS 256

#define SPACING (12.0f / (float)(G_NUM - 1))
#define INV_SPACING ((float)(G_NUM - 1) / 12.0f)
#define RBF_COEFF (-0.5f * ((float)G_NUM / 12.0f) * ((float)G_NUM / 12.0f))

// ---------------- Pass 0: transpose emb [p][h][g] -> [p][g][h] ----------------
__global__ __launch_bounds__(BLOCK_THREADS) void transpose_kernel(
    const float* __restrict__ emb, float* __restrict__ temb)
{
    int idx = blockIdx.x * BLOCK_THREADS + threadIdx.x;
    if (idx < N_PAIRS * H_NUM * G_NUM) {
        int p = idx / (H_NUM * G_NUM);
        int r = idx - p * (H_NUM * G_NUM);
        int g = r >> 3;
        int h = r & 7;
        temb[idx] = emb[p * (H_NUM * G_NUM) + h * G_NUM + g];
    }
}

// ---------------- Pass A: bin edges by sa, LDS-aggregated ----------------
__global__ __launch_bounds__(BLOCK_THREADS) void binA_kernel(
    const int* __restrict__ anum,
    const int* __restrict__ edge_index,
    const float* __restrict__ dist,
    const float* __restrict__ emb,
    int* __restrict__ gcnt,           // [NE_NUM * ASUBS], pre-zeroed
    uint2* __restrict__ bucket,       // [NE_NUM * ASUBS * SUBCAP]
    float* __restrict__ out,          // slow-path only
    int n_edges, int epb)
{
    __shared__ int c1[NE_NUM];
    __shared__ int c2[NE_NUM];
    __shared__ int base_s[NE_NUM];
    __shared__ unsigned char sac[SA_CACHE];

    const int tid = threadIdx.x;
    const int blk = blockIdx.x;
    const int sub = blk & (ASUBS - 1);
    const int e0  = blk * epb;
    int e1 = e0 + epb;
    if (e1 > n_edges) e1 = n_edges;

    if (tid < NE_NUM) { c1[tid] = 0; c2[tid] = 0; }
    __syncthreads();

    // Sweep 1: LDS histogram of sa, cache sa per edge.
    for (int b = e0; b < e1; b += BLOCK_THREADS) {
        int e = b + tid;
        if (e < e1) {
            int s  = edge_index[e];
            int sa = anum[s];
            int ci = b - e0 + tid;
            if (ci < SA_CACHE) sac[ci] = (unsigned char)sa;
            atomicAdd(&c1[sa], 1);
        }
    }
    __syncthreads();

    // One returning global atomic per nonzero bin.
    if (tid < NE_NUM)
        base_s[tid] = c1[tid] ? atomicAdd(&gcnt[tid * ASUBS + sub], c1[tid]) : 0;
    __syncthreads();

    // Sweep 2: place entries. Writes cluster per (bin,block) -> L2 coalesces.
    for (int b = e0; b < e1; b += BLOCK_THREADS) {
        int e = b + tid;
        if (e < e1) {
            int ci = b - e0 + tid;
            int sa = (ci < SA_CACHE) ? (int)sac[ci] : anum[edge_index[e]];
            int d  = edge_index[n_edges + e];
            int da = anum[d];
            float dv = dist[e];
            int pos = base_s[sa] + atomicAdd(&c2[sa], 1);
            if (pos < SUBCAP) {
                uint2 ent;
                ent.x = __float_as_uint(dv);
                ent.y = ((unsigned)e << 7) | (unsigned)da;
                bucket[(size_t)(sa * ASUBS + sub) * SUBCAP + pos] = ent;
            } else {
                // Overflow slow path: exact full-width dot from original emb.
                const float* ar = emb + (size_t)(sa * NE_NUM + da) * (H_NUM * G_NUM);
                for (int h = 0; h < H_NUM; ++h) {
                    float acc = 0.0f;
                    for (int g = 0; g < G_NUM; ++g) {
                        float diff = dv - (float)g * SPACING;
                        acc += ar[h * G_NUM + g] * __expf(RBF_COEFF * diff * diff);
                    }
                    out[(size_t)e * H_NUM + h] = acc;
                }
            }
        }
    }
}

// ---------------- Pass C: compute, sa-major for L2 locality ----------------
__global__ __launch_bounds__(BLOCK_THREADS) void computeC_kernel(
    const float* __restrict__ temb,
    const int* __restrict__ gcnt,
    const uint2* __restrict__ bucket,
    float* __restrict__ out)
{
    __shared__ uint2 ent_s[CCHUNK];

    const int bid = blockIdx.x;
    const int sa    = bid / (ASUBS * NCHUNK);
    const int r     = bid - sa * (ASUBS * NCHUNK);
    const int sub   = r / NCHUNK;
    const int chunk = r - sub * NCHUNK;

    int cnt = gcnt[sa * ASUBS + sub];
    if (cnt > SUBCAP) cnt = SUBCAP;
    int n = cnt - chunk * CCHUNK;
    if (n <= 0) return;
    if (n > CCHUNK) n = CCHUNK;

    const int tid = threadIdx.x;
    if (tid < CCHUNK && tid < n)
        ent_s[tid] = bucket[(size_t)(sa * ASUBS + sub) * SUBCAP + chunk * CCHUNK + tid];
    __syncthreads();

    const int el = tid >> 3;
    const int j  = tid & 7;
    if (el >= n) return;

    uint2 ent = ent_s[el];
    float dv  = __uint_as_float(ent.x);
    int   e   = (int)(ent.y >> 7);
    int   da  = (int)(ent.y & 127);

    int g0 = (int)(dv * INV_SPACING) - 7;
    if (g0 < 0) g0 = 0;
    if (g0 > G_NUM - WIN) g0 = G_NUM - WIN;
    g0 &= ~1;   // even -> window is 64B-aligned in temb

    // Window: temb[p][g0..g0+15][0..7], 512B contiguous. Lane j loads chunks
    // j, j+8, j+16, j+24 (float4 each): element (g = g0 + (c>>1), h = (c&1)*4 + m).
    const float* wbase = temb + ((size_t)(sa * NE_NUM + da) * (H_NUM * G_NUM) + g0 * H_NUM);

    float4 acc = make_float4(0.f, 0.f, 0.f, 0.f);
    #pragma unroll
    for (int k = 0; k < 4; ++k) {
        int c = j + 8 * k;
        float4 v = *(const float4*)(wbase + 4 * c);
        float diff = dv - (float)(g0 + (c >> 1)) * SPACING;
        float rb = __expf(RBF_COEFF * diff * diff);
        acc.x += rb * v.x;
        acc.y += rb * v.y;
        acc.z += rb * v.z;
        acc.w += rb * v.w;
    }

    // Butterfly over lanes j^2, j^4 (same parity = same h-half).
    acc.x += __shfl_xor(acc.x, 2); acc.y += __shfl_xor(acc.y, 2);
    acc.z += __shfl_xor(acc.z, 2); acc.w += __shfl_xor(acc.w, 2);
    acc.x += __shfl_xor(acc.x, 4); acc.y += __shfl_xor(acc.y, 4);
    acc.z += __shfl_xor(acc.z, 4); acc.w += __shfl_xor(acc.w, 4);

    if (j < 2) {
        // j==0 holds h0-3, j==1 holds h4-7.
        *(float4*)(out + (size_t)e * H_NUM + j * 4) = acc;
    }
}

// ---------------- Fallback: direct (R1) kernel, ws-free ----------------
__global__ __launch_bounds__(BLOCK_THREADS) void direct_kernel(
    const int* __restrict__ anum,
    const int* __restrict__ edge_index,
    const float* __restrict__ dist,
    const float* __restrict__ emb,
    float* __restrict__ out,
    int n_edges)
{
    __shared__ int   pair_s[32];
    __shared__ float dist_sd[32];
    __shared__ float rbf_sd[32 * G_NUM];

    const int tid = threadIdx.x;
    const int e0  = blockIdx.x * 32;

    if (tid < 32) {
        int e = e0 + tid;
        if (e >= n_edges) e = n_edges - 1;
        int s  = edge_index[e];
        int d  = edge_index[n_edges + e];
        pair_s[tid] = (anum[s] * NE_NUM + anum[d]) * (H_NUM * G_NUM);
        dist_sd[tid] = dist[e];
    }
    __syncthreads();

    for (int idx = tid; idx < 32 * G_NUM; idx += BLOCK_THREADS) {
        int el = idx / G_NUM;
        int g  = idx - el * G_NUM;
        float diff = dist_sd[el] - (float)g * SPACING;
        rbf_sd[idx] = __expf(RBF_COEFF * diff * diff);
    }
    __syncthreads();

    const int el = tid >> 3;
    const int h  = tid & 7;
    const float* ebase = emb + pair_s[el] + h * G_NUM;
    const float* rbase = rbf_sd + el * G_NUM;

    float acc = 0.0f;
    #pragma unroll
    for (int g2 = 0; g2 < G_NUM / 2; ++g2) {
        float2 ev = *(const float2*)(ebase + 2 * g2);
        float2 rv = *(const float2*)(rbase + 2 * g2);
        acc += ev.x * rv.x + ev.y * rv.y;
    }

    if (e0 + el < n_edges)
        out[e0 * H_NUM + tid] = acc;
}

extern "C" void kernel_launch(void* const* d_in, const int* in_sizes, int n_in,
                              void* d_out, int out_size, void* d_ws, size_t ws_size,
                              hipStream_t stream) {
    const int*   anum       = (const int*)d_in[0];
    const int*   edge_index = (const int*)d_in[1];
    const float* dist       = (const float*)d_in[2];
    const float* emb        = (const float*)d_in[3];
    float*       out        = (float*)d_out;
    const int n_edges = in_sizes[2];

    // ws layout: [gcnt: 100*32 ints][bucket: 100*32*448 uint2][temb: 4M floats]
    const size_t gcnt_bytes   = (size_t)NE_NUM * ASUBS * sizeof(int);          // 12.8 KB
    const size_t bucket_off   = 16384;
    const size_t bucket_bytes = (size_t)NE_NUM * ASUBS * SUBCAP * sizeof(uint2); // 11.47 MB
    const size_t temb_off     = bucket_off + bucket_bytes;                     // 1KB-aligned
    const size_t temb_bytes   = (size_t)N_PAIRS * H_NUM * G_NUM * sizeof(float); // 16 MB
    const size_t need = temb_off + temb_bytes;                                 // ~27.5 MB

    if (ws_size < need) {
        const int grid = (n_edges + 31) / 32;
        direct_kernel<<<grid, BLOCK_THREADS, 0, stream>>>(
            anum, edge_index, dist, emb, out, n_edges);
        return;
    }

    int*   gcnt   = (int*)d_ws;
    uint2* bucket = (uint2*)((char*)d_ws + bucket_off);
    float* temb   = (float*)((char*)d_ws + temb_off);

    hipMemsetAsync(gcnt, 0, gcnt_bytes, stream);

    const int tgrid = (N_PAIRS * H_NUM * G_NUM + BLOCK_THREADS - 1) / BLOCK_THREADS;
    transpose_kernel<<<tgrid, BLOCK_THREADS, 0, stream>>>(emb, temb);

    const int epb = (n_edges + ABLOCKS - 1) / ABLOCKS;
    binA_kernel<<<ABLOCKS, BLOCK_THREADS, 0, stream>>>(
        anum, edge_index, dist, emb, gcnt, bucket, out, n_edges, epb);

    computeC_kernel<<<NE_NUM * ASUBS * NCHUNK, BLOCK_THREADS, 0, stream>>>(
        temb, gcnt, bucket, out);
}

// Round 5
// 131.520 us; speedup vs baseline: 2.1806x; 1.2114x over previous
//
#include <hip/hip_runtime.h>

// EfficientPairEmbed: out[0, e, h] = sum_g emb[anum[src_e], anum[dst_e], 0, h, g] * rbf[e, g]
// rbf[e,g] = exp(-0.5/std^2 * (dist_e - offset_g)^2), offsets = linspace(0, 12, 50), std = 12/50.
//
// R5: no binning. Table transposed to [p][g][h] and cast to bf16: an edge's
// 16-gaussian window is 256B contiguous (4 cache lines) and the whole table is
// 8MB (~aggregate-L2 resident). Direct per-edge gather with 2 lanes/edge,
// 8 independent 16B loads per lane for MLP. R4 post-mortem: binning passes
// cost ~45us each and bought nothing once the gather is line-contiguous.

#define G_NUM 50
#define H_NUM 8
#define NE_NUM 100
#define N_PAIRS (NE_NUM * NE_NUM)
#define WIN 16
#define BLOCK_THREADS 256
#define EDGES_PER_BLOCK 128     // 2 lanes per edge

#define SPACING (12.0f / (float)(G_NUM - 1))
#define INV_SPACING ((float)(G_NUM - 1) / 12.0f)
#define RBF_COEFF (-0.5f * ((float)G_NUM / 12.0f) * ((float)G_NUM / 12.0f))

// ---------------- Pass 0: emb [p][h][g] fp32 -> temb [p][g][h] bf16 (RN) ----------------
__global__ __launch_bounds__(BLOCK_THREADS) void transpose_cast_kernel(
    const float* __restrict__ emb, unsigned short* __restrict__ temb)
{
    int idx = blockIdx.x * BLOCK_THREADS + threadIdx.x;
    if (idx < N_PAIRS * H_NUM * G_NUM) {
        int p = idx / (H_NUM * G_NUM);
        int r = idx - p * (H_NUM * G_NUM);
        int g = r >> 3;
        int h = r & 7;
        float f = emb[p * (H_NUM * G_NUM) + h * G_NUM + g];
        unsigned u = __float_as_uint(f);
        unsigned rnd = (u + 0x7fffu + ((u >> 16) & 1u)) >> 16;   // round-to-nearest-even
        temb[idx] = (unsigned short)rnd;
    }
}

// ---------------- Pass 1: direct windowed gather ----------------
__global__ __launch_bounds__(BLOCK_THREADS) void gather_kernel(
    const int* __restrict__ anum,
    const int* __restrict__ edge_index,
    const float* __restrict__ dist,
    const unsigned short* __restrict__ temb,
    float* __restrict__ out,
    int n_edges)
{
    __shared__ int   pb_s[EDGES_PER_BLOCK];
    __shared__ float dv_s[EDGES_PER_BLOCK];

    const int tid = threadIdx.x;
    const int e0  = blockIdx.x * EDGES_PER_BLOCK;

    if (tid < EDGES_PER_BLOCK) {
        int e = e0 + tid;
        if (e >= n_edges) e = n_edges - 1;
        int s = edge_index[e];
        int d = edge_index[n_edges + e];
        pb_s[tid] = (anum[s] * NE_NUM + anum[d]) * (H_NUM * G_NUM);
        dv_s[tid] = dist[e];
    }
    __syncthreads();

    const int el = tid >> 1;     // 0..127
    const int j  = tid & 1;      // lane within edge
    const float dv = dv_s[el];

    int g0 = (int)(dv * INV_SPACING) - 7;
    if (g0 < 0) g0 = 0;
    if (g0 > G_NUM - WIN) g0 = G_NUM - WIN;

    // Window rows are 16B each ([g][h0..7] bf16); lane j takes rows 2k+j.
    const unsigned short* wb = temb + pb_s[el] + g0 * H_NUM;

    float a0 = 0.f, a1 = 0.f, a2 = 0.f, a3 = 0.f;
    float a4 = 0.f, a5 = 0.f, a6 = 0.f, a7 = 0.f;
    #pragma unroll
    for (int k = 0; k < WIN / 2; ++k) {
        int row = 2 * k + j;
        uint4 v = *(const uint4*)(wb + row * H_NUM);
        float diff = dv - (float)(g0 + row) * SPACING;
        float rb = __expf(RBF_COEFF * diff * diff);
        a0 += rb * __uint_as_float(v.x << 16);
        a1 += rb * __uint_as_float(v.x & 0xffff0000u);
        a2 += rb * __uint_as_float(v.y << 16);
        a3 += rb * __uint_as_float(v.y & 0xffff0000u);
        a4 += rb * __uint_as_float(v.z << 16);
        a5 += rb * __uint_as_float(v.z & 0xffff0000u);
        a6 += rb * __uint_as_float(v.w << 16);
        a7 += rb * __uint_as_float(v.w & 0xffff0000u);
    }

    // Combine the two lanes of this edge.
    a0 += __shfl_xor(a0, 1); a1 += __shfl_xor(a1, 1);
    a2 += __shfl_xor(a2, 1); a3 += __shfl_xor(a3, 1);
    a4 += __shfl_xor(a4, 1); a5 += __shfl_xor(a5, 1);
    a6 += __shfl_xor(a6, 1); a7 += __shfl_xor(a7, 1);

    int e = e0 + el;
    if (e < n_edges) {
        float4 w = j ? make_float4(a4, a5, a6, a7) : make_float4(a0, a1, a2, a3);
        *(float4*)(out + (size_t)e * H_NUM + 4 * j) = w;   // 32B per edge, coalesced
    }
}

// ---------------- Fallback (ws-free): R1 direct kernel on fp32 emb ----------------
__global__ __launch_bounds__(BLOCK_THREADS) void direct_kernel(
    const int* __restrict__ anum,
    const int* __restrict__ edge_index,
    const float* __restrict__ dist,
    const float* __restrict__ emb,
    float* __restrict__ out,
    int n_edges)
{
    __shared__ int   pair_s[32];
    __shared__ float dist_sd[32];
    __shared__ float rbf_sd[32 * G_NUM];

    const int tid = threadIdx.x;
    const int e0  = blockIdx.x * 32;

    if (tid < 32) {
        int e = e0 + tid;
        if (e >= n_edges) e = n_edges - 1;
        int s  = edge_index[e];
        int d  = edge_index[n_edges + e];
        pair_s[tid] = (anum[s] * NE_NUM + anum[d]) * (H_NUM * G_NUM);
        dist_sd[tid] = dist[e];
    }
    __syncthreads();

    for (int idx = tid; idx < 32 * G_NUM; idx += BLOCK_THREADS) {
        int el = idx / G_NUM;
        int g  = idx - el * G_NUM;
        float diff = dist_sd[el] - (float)g * SPACING;
        rbf_sd[idx] = __expf(RBF_COEFF * diff * diff);
    }
    __syncthreads();

    const int el = tid >> 3;
    const int h  = tid & 7;
    const float* ebase = emb + pair_s[el] + h * G_NUM;
    const float* rbase = rbf_sd + el * G_NUM;

    float acc = 0.0f;
    #pragma unroll
    for (int g2 = 0; g2 < G_NUM / 2; ++g2) {
        float2 ev = *(const float2*)(ebase + 2 * g2);
        float2 rv = *(const float2*)(rbase + 2 * g2);
        acc += ev.x * rv.x + ev.y * rv.y;
    }

    if (e0 + el < n_edges)
        out[e0 * H_NUM + tid] = acc;
}

extern "C" void kernel_launch(void* const* d_in, const int* in_sizes, int n_in,
                              void* d_out, int out_size, void* d_ws, size_t ws_size,
                              hipStream_t stream) {
    const int*   anum       = (const int*)d_in[0];
    const int*   edge_index = (const int*)d_in[1];
    const float* dist       = (const float*)d_in[2];
    const float* emb        = (const float*)d_in[3];
    float*       out        = (float*)d_out;
    const int n_edges = in_sizes[2];

    const size_t temb_bytes = (size_t)N_PAIRS * H_NUM * G_NUM * sizeof(unsigned short); // 8 MB

    if (ws_size < temb_bytes) {
        const int grid = (n_edges + 31) / 32;
        direct_kernel<<<grid, BLOCK_THREADS, 0, stream>>>(
            anum, edge_index, dist, emb, out, n_edges);
        return;
    }

    unsigned short* temb = (unsigned short*)d_ws;

    const int tgrid = (N_PAIRS * H_NUM * G_NUM + BLOCK_THREADS - 1) / BLOCK_THREADS;
    transpose_cast_kernel<<<tgrid, BLOCK_THREADS, 0, stream>>>(emb, temb);

    const int grid = (n_edges + EDGES_PER_BLOCK - 1) / EDGES_PER_BLOCK;
    gather_kernel<<<grid, BLOCK_THREADS, 0, stream>>>(
        anum, edge_index, dist, temb, out, n_edges);
}

// Round 6
// 112.795 us; speedup vs baseline: 2.5426x; 1.1660x over previous
//
#include <hip/hip_runtime.h>

// EfficientPairEmbed: out[0, e, h] = sum_g emb[anum[src_e], anum[dst_e], 0, h, g] * rbf[e, g]
// rbf[e,g] = exp(-0.5/std^2 * (dist_e - offset_g)^2), offsets = linspace(0, 12, 50), std = 12/50.
//
// R6: gather is random-line-fetch-BW bound (~3 TB/s plateau seen in R1/R4/R5).
// Attack bytes: (1) WIN 16->8 (tail terms < 2.5e-4; window 256B->128B),
// one lane per edge, 8 independent 16B loads, no LDS/shfl.
// (2) transpose pass restaged through LDS: coalesced reads AND writes
// (R5's scattered-read transpose was costing ~20us).

#define G_NUM 50
#define H_NUM 8
#define NE_NUM 100
#define N_PAIRS (NE_NUM * NE_NUM)
#define WIN 8
#define BLOCK_THREADS 256
#define TP_PAIRS 8               // pairs per transpose block

#define SPACING (12.0f / (float)(G_NUM - 1))
#define INV_SPACING ((float)(G_NUM - 1) / 12.0f)
#define RBF_COEFF (-0.5f * ((float)G_NUM / 12.0f) * ((float)G_NUM / 12.0f))

__device__ __forceinline__ float bf_lo(unsigned u) { return __uint_as_float(u << 16); }
__device__ __forceinline__ float bf_hi(unsigned u) { return __uint_as_float(u & 0xffff0000u); }

// ---------------- Pass 0: emb [p][h][g] fp32 -> temb [p][g][h] bf16, LDS-staged ----------------
__global__ __launch_bounds__(BLOCK_THREADS) void transpose_cast_kernel(
    const float* __restrict__ emb, unsigned int* __restrict__ temb)
{
    __shared__ float ls[TP_PAIRS * H_NUM * G_NUM];          // 3200 floats, 12.8 KB

    const int tid = threadIdx.x;
    const int p0  = blockIdx.x * TP_PAIRS;

    // Coalesced read: 800 float4 per block.
    const float4* src = (const float4*)(emb + (size_t)p0 * (H_NUM * G_NUM));
    #pragma unroll
    for (int i = tid; i < TP_PAIRS * H_NUM * G_NUM / 4; i += BLOCK_THREADS)
        ((float4*)ls)[i] = src[i];
    __syncthreads();

    // Coalesced write: 1600 packed-bf16 uints per block.
    unsigned int* dst = temb + (size_t)p0 * (H_NUM * G_NUM / 2);
    #pragma unroll
    for (int i = tid; i < TP_PAIRS * H_NUM * G_NUM / 2; i += BLOCK_THREADS) {
        int q  = i / (H_NUM * G_NUM / 2);          // local pair
        int u  = i - q * (H_NUM * G_NUM / 2);      // uint idx within pair: [g][h/2]
        int g  = u >> 2;
        int h0 = (u & 3) * 2;
        float f0 = ls[q * (H_NUM * G_NUM) + h0 * G_NUM + g];
        float f1 = ls[q * (H_NUM * G_NUM) + (h0 + 1) * G_NUM + g];
        unsigned u0 = __float_as_uint(f0);
        unsigned u1 = __float_as_uint(f1);
        unsigned b0 = (u0 + 0x7fffu + ((u0 >> 16) & 1u)) >> 16;   // RNE bf16
        unsigned b1 = (u1 + 0x7fffu + ((u1 >> 16) & 1u)) >> 16;
        dst[i] = (b1 << 16) | (b0 & 0xffffu);
    }
}

// ---------------- Pass 1: direct windowed gather, 1 lane/edge ----------------
__global__ __launch_bounds__(BLOCK_THREADS) void gather_kernel(
    const int* __restrict__ anum,
    const int* __restrict__ edge_index,
    const float* __restrict__ dist,
    const unsigned short* __restrict__ temb,
    float* __restrict__ out,
    int n_edges)
{
    int e = blockIdx.x * BLOCK_THREADS + threadIdx.x;
    if (e >= n_edges) return;

    int s = edge_index[e];
    int d = edge_index[n_edges + e];
    int p = anum[s] * NE_NUM + anum[d];
    float dv = dist[e];

    int g0 = (int)(dv * INV_SPACING) - 3;
    if (g0 < 0) g0 = 0;
    if (g0 > G_NUM - WIN) g0 = G_NUM - WIN;

    // Window rows are 16B each ([g][h0..7] bf16), 128B contiguous total.
    const unsigned short* wb = temb + (size_t)p * (H_NUM * G_NUM) + g0 * H_NUM;

    uint4 v[WIN];
    #pragma unroll
    for (int r = 0; r < WIN; ++r)
        v[r] = *(const uint4*)(wb + r * H_NUM);      // 8 independent 16B loads

    float a0 = 0.f, a1 = 0.f, a2 = 0.f, a3 = 0.f;
    float a4 = 0.f, a5 = 0.f, a6 = 0.f, a7 = 0.f;
    #pragma unroll
    for (int r = 0; r < WIN; ++r) {
        float diff = dv - (float)(g0 + r) * SPACING;
        float rb = __expf(RBF_COEFF * diff * diff);
        a0 += rb * bf_lo(v[r].x);
        a1 += rb * bf_hi(v[r].x);
        a2 += rb * bf_lo(v[r].y);
        a3 += rb * bf_hi(v[r].y);
        a4 += rb * bf_lo(v[r].z);
        a5 += rb * bf_hi(v[r].z);
        a6 += rb * bf_lo(v[r].w);
        a7 += rb * bf_hi(v[r].w);
    }

    float* ob = out + (size_t)e * H_NUM;
    *(float4*)(ob)     = make_float4(a0, a1, a2, a3);   // coalesced 32B/thread
    *(float4*)(ob + 4) = make_float4(a4, a5, a6, a7);
}

// ---------------- Fallback (ws-free): exact fp32 direct kernel ----------------
__global__ __launch_bounds__(BLOCK_THREADS) void direct_kernel(
    const int* __restrict__ anum,
    const int* __restrict__ edge_index,
    const float* __restrict__ dist,
    const float* __restrict__ emb,
    float* __restrict__ out,
    int n_edges)
{
    __shared__ int   pair_s[32];
    __shared__ float dist_sd[32];
    __shared__ float rbf_sd[32 * G_NUM];

    const int tid = threadIdx.x;
    const int e0  = blockIdx.x * 32;

    if (tid < 32) {
        int e = e0 + tid;
        if (e >= n_edges) e = n_edges - 1;
        int s  = edge_index[e];
        int d  = edge_index[n_edges + e];
        pair_s[tid] = (anum[s] * NE_NUM + anum[d]) * (H_NUM * G_NUM);
        dist_sd[tid] = dist[e];
    }
    __syncthreads();

    for (int idx = tid; idx < 32 * G_NUM; idx += BLOCK_THREADS) {
        int el = idx / G_NUM;
        int g  = idx - el * G_NUM;
        float diff = dist_sd[el] - (float)g * SPACING;
        rbf_sd[idx] = __expf(RBF_COEFF * diff * diff);
    }
    __syncthreads();

    const int el = tid >> 3;
    const int h  = tid & 7;
    const float* ebase = emb + pair_s[el] + h * G_NUM;
    const float* rbase = rbf_sd + el * G_NUM;

    float acc = 0.0f;
    #pragma unroll
    for (int g2 = 0; g2 < G_NUM / 2; ++g2) {
        float2 ev = *(const float2*)(ebase + 2 * g2);
        float2 rv = *(const float2*)(rbase + 2 * g2);
        acc += ev.x * rv.x + ev.y * rv.y;
    }

    if (e0 + el < n_edges)
        out[e0 * H_NUM + tid] = acc;
}

extern "C" void kernel_launch(void* const* d_in, const int* in_sizes, int n_in,
                              void* d_out, int out_size, void* d_ws, size_t ws_size,
                              hipStream_t stream) {
    const int*   anum       = (const int*)d_in[0];
    const int*   edge_index = (const int*)d_in[1];
    const float* dist       = (const float*)d_in[2];
    const float* emb        = (const float*)d_in[3];
    float*       out        = (float*)d_out;
    const int n_edges = in_sizes[2];

    const size_t temb_bytes = (size_t)N_PAIRS * H_NUM * G_NUM * sizeof(unsigned short); // 8 MB

    if (ws_size < temb_bytes) {
        const int grid = (n_edges + 31) / 32;
        direct_kernel<<<grid, BLOCK_THREADS, 0, stream>>>(
            anum, edge_index, dist, emb, out, n_edges);
        return;
    }

    unsigned int* temb = (unsigned int*)d_ws;

    transpose_cast_kernel<<<N_PAIRS / TP_PAIRS, BLOCK_THREADS, 0, stream>>>(emb, temb);

    const int grid = (n_edges + BLOCK_THREADS - 1) / BLOCK_THREADS;
    gather_kernel<<<grid, BLOCK_THREADS, 0, stream>>>(
        anum, edge_index, dist, (const unsigned short*)temb, out, n_edges);
}